// Round 8
// baseline (614.451 us; speedup 1.0000x reference)
//
#include <hip/hip_runtime.h>
#include <cstdint>

typedef __attribute__((ext_vector_type(8))) short short8;
typedef __attribute__((ext_vector_type(4))) float f32x4;

#define DEVINL static __device__ __forceinline__

DEVINL ushort f2b(float f) {
    uint32_t u = __builtin_bit_cast(uint32_t, f);
    u += 0x7FFFu + ((u >> 16) & 1u);
    return (ushort)(u >> 16);
}

typedef __attribute__((address_space(3))) uint32_t lds_u32;
typedef const __attribute__((address_space(1))) uint32_t glb_u32;

DEVINL void load_lds_16(const ushort* g, ushort* l) {
    __builtin_amdgcn_global_load_lds((glb_u32*)g, (lds_u32*)l, 16, 0, 0);
}

// ---------------------------------------------------------------------------
// gemm_k_dev: C[M,N] tile (64x64) = A @ BT^T (+bias, epilogues), LDS-staged.
// ---------------------------------------------------------------------------
constexpr int EPI_F32      = 0;
constexpr int EPI_MUL_BF16 = 2;
constexpr int EPI_SCALE_FB = 3;

template<int K, int EPI>
DEVINL void gemm_k_dev(
    const ushort* __restrict__ A, const ushort* __restrict__ BT,
    const float* __restrict__ bias, int N,
    float* __restrict__ outf, ushort* __restrict__ outb, int obld, int oboff,
    const float* __restrict__ extra, int bx, int by,
    ushort* Asm, ushort* Bsm)
{
    const int wave = threadIdx.x >> 6;
    const int lane = threadIdx.x & 63;
    const int quad = lane >> 4, l16 = lane & 15;
    const int lr = lane >> 3, ls = lane & 7;
    const int m0 = bx * 64, n0 = by * 64;

    f32x4 zero = {0.f, 0.f, 0.f, 0.f};
    f32x4 acc[4] = {zero, zero, zero, zero};

    for (int k0 = 0; k0 < K; k0 += 64) {
        #pragma unroll
        for (int p = 0; p < 2; ++p) {
            const int r = wave * 16 + p * 8 + lr;
            load_lds_16(A + (size_t)(m0 + r) * K + k0 + ((ls ^ (r & 7)) * 8),
                        Asm + (size_t)(wave * 16 + p * 8) * 64);
            load_lds_16(BT + (size_t)(n0 + r) * K + k0 + ((ls ^ (r & 7)) * 8),
                        Bsm + (size_t)(wave * 16 + p * 8) * 64);
        }
        __syncthreads();
        #pragma unroll
        for (int ks = 0; ks < 2; ++ks) {
            const int sl = ((ks * 4 + quad) ^ (l16 & 7)) * 8;
            short8 af = *(const short8*)(Asm + (wave * 16 + l16) * 64 + sl);
            #pragma unroll
            for (int c = 0; c < 4; ++c) {
                short8 bf = *(const short8*)(Bsm + (c * 16 + l16) * 64 + sl);
                acc[c] = __builtin_amdgcn_mfma_f32_16x16x32_bf16(af, bf, acc[c], 0, 0, 0);
            }
        }
        __syncthreads();
    }

    #pragma unroll
    for (int r = 0; r < 4; ++r) {
        const int row = m0 + wave * 16 + quad * 4 + r;
        #pragma unroll
        for (int c = 0; c < 4; ++c) {
            const int col = n0 + c * 16 + l16;
            float v = acc[c][r] + (bias ? bias[col] : 0.f);
            if (EPI == EPI_MUL_BF16) v *= extra[(size_t)row * N + col];
            if (EPI == EPI_SCALE_FB) v *= extra[row];
            if (EPI == EPI_F32 || EPI == EPI_SCALE_FB)
                outf[(size_t)row * N + col] = v;
            if (EPI == EPI_MUL_BF16 || EPI == EPI_SCALE_FB)
                outb[(size_t)row * obld + oboff + col] = f2b(v);
        }
    }
}

// ---------------------------------------------------------------------------
// gemm_wh: Wh = hbf @ wT. Writes Wh f32, Whbf, and WhF (fragment-major bf16
// layout for attn: WhF[jb][fb][lane][8], lane l holds
// Wh[jb*32+(l>>4)*8+e][fb*16+(l&15)] — one coalesced 16B load per B-frag),
// plus fused s/d row-dot atomics.
// ---------------------------------------------------------------------------
__global__ __launch_bounds__(256) void gemm_wh_kernel(
    const ushort* __restrict__ A, const ushort* __restrict__ BT,
    const float* __restrict__ asrc, const float* __restrict__ adst,
    float* __restrict__ Wh, ushort* __restrict__ Whbf, ushort* __restrict__ WhF,
    float* __restrict__ sOut, float* __restrict__ dOut)
{
    __shared__ ushort smem[2 * 64 * 64];
    ushort* Asm = smem;
    ushort* Bsm = smem + 4096;
    constexpr int K = 256;

    const int tid = threadIdx.x;
    const int wave = tid >> 6, lane = tid & 63;
    const int quad = lane >> 4, l16 = lane & 15;
    const int lr = lane >> 3, ls = lane & 7;
    const int m0 = blockIdx.x * 64, n0 = blockIdx.y * 64;

    f32x4 zero = {0.f, 0.f, 0.f, 0.f};
    f32x4 acc[4] = {zero, zero, zero, zero};

    for (int k0 = 0; k0 < K; k0 += 64) {
        #pragma unroll
        for (int p = 0; p < 2; ++p) {
            const int r = wave * 16 + p * 8 + lr;
            load_lds_16(A + (size_t)(m0 + r) * K + k0 + ((ls ^ (r & 7)) * 8),
                        Asm + (size_t)(wave * 16 + p * 8) * 64);
            load_lds_16(BT + (size_t)(n0 + r) * K + k0 + ((ls ^ (r & 7)) * 8),
                        Bsm + (size_t)(wave * 16 + p * 8) * 64);
        }
        __syncthreads();
        #pragma unroll
        for (int ks = 0; ks < 2; ++ks) {
            const int sl = ((ks * 4 + quad) ^ (l16 & 7)) * 8;
            short8 af = *(const short8*)(Asm + (wave * 16 + l16) * 64 + sl);
            #pragma unroll
            for (int c = 0; c < 4; ++c) {
                short8 bf = *(const short8*)(Bsm + (c * 16 + l16) * 64 + sl);
                acc[c] = __builtin_amdgcn_mfma_f32_16x16x32_bf16(af, bf, acc[c], 0, 0, 0);
            }
        }
        __syncthreads();
    }

    ushort* Tsm = smem;    // [col 0..64)][row 0..64) bf16, stride 72
    #pragma unroll
    for (int r = 0; r < 4; ++r) {
        const int rl = wave * 16 + quad * 4 + r;
        const int row = m0 + rl;
        float sp = 0.f, dp = 0.f;
        #pragma unroll
        for (int c = 0; c < 4; ++c) {
            const int cl = c * 16 + l16;
            const int col = n0 + cl;
            const float v = acc[c][r];
            Wh[(size_t)row * 256 + col] = v;
            const ushort b = f2b(v);
            Whbf[(size_t)row * 256 + col] = b;
            Tsm[cl * 72 + rl] = b;
            sp += v * asrc[col]; dp += v * adst[col];
        }
        #pragma unroll
        for (int o = 1; o < 16; o <<= 1) {
            sp += __shfl_xor(sp, o);
            dp += __shfl_xor(dp, o);
        }
        if (l16 == 0) {
            atomicAdd(&sOut[row], sp);
            atomicAdd(&dOut[row], dp);
        }
    }
    __syncthreads();
    // WhF fragments: jbl 0..2 (j 32-blocks), wave w handles fb = n0/16 + w.
    const int jb0 = m0 >> 5, fb0 = n0 >> 4;
    #pragma unroll
    for (int jbl = 0; jbl < 2; ++jbl) {
        uint4 v = *(const uint4*)(Tsm + (wave * 16 + l16) * 72 + jbl * 32 + quad * 8);
        *(uint4*)(WhF + ((size_t)((jb0 + jbl) * 16 + fb0 + wave) * 64 + lane) * 8) = v;
    }
}

// ---------------------------------------------------------------------------
// gemm_row_dev: BM=16 rows, full N, fused row-local epilogues.
// ---------------------------------------------------------------------------
constexpr int EPR_LNSILU = 0;
constexpr int EPR_BCDT   = 1;
constexpr int EPR_HZ     = 2;
constexpr int EPR_FINAL  = 3;

template<int K, int N, int EPI>
DEVINL void gemm_row_dev(
    const ushort* __restrict__ A, const ushort* __restrict__ BT,
    const float* __restrict__ bias,
    float* __restrict__ outf, ushort* __restrict__ outb,
    const float* __restrict__ q0, const float* __restrict__ q1,
    const float* __restrict__ q2, const float* __restrict__ q3,
    const float* __restrict__ q4,
    int bx, int by, ushort* Asm, ushort* Bsm, float* red)
{
    constexpr int NW = N / 4;
    constexpr int NF = NW / 16;

    const int wave = threadIdx.x >> 6;
    const int lane = threadIdx.x & 63;
    const int quad = lane >> 4, l16 = lane & 15;
    const int lr = lane >> 3, ls = lane & 7;
    const int m0 = bx * 16;
    const ushort* Bb = BT + (EPI == EPR_HZ ? (size_t)by * 512 * K : 0);

    f32x4 zero = {0.f, 0.f, 0.f, 0.f};
    f32x4 acc[NF];
    #pragma unroll
    for (int c = 0; c < NF; ++c) acc[c] = zero;

    for (int k0 = 0; k0 < K; k0 += 64) {
        if (wave < 2) {
            const int r = wave * 8 + lr;
            load_lds_16(A + (size_t)(m0 + r) * K + k0 + ((ls ^ (r & 7)) * 8),
                        Asm + (size_t)(wave * 8) * 64);
        }
        #pragma unroll
        for (int p = 0; p < NW / 8; ++p) {
            const int n = wave * NW + p * 8 + lr;
            load_lds_16(Bb + (size_t)n * K + k0 + ((ls ^ (n & 7)) * 8),
                        Bsm + (size_t)(wave * NW + p * 8) * 64);
        }
        __syncthreads();
        #pragma unroll
        for (int ks = 0; ks < 2; ++ks) {
            const int sl = ((ks * 4 + quad) ^ (l16 & 7)) * 8;
            short8 af = *(const short8*)(Asm + l16 * 64 + sl);
            #pragma unroll
            for (int c = 0; c < NF; ++c) {
                const int gf = (EPI == EPR_BCDT) ? (wave + 4 * c) : (wave * NF + c);
                short8 bf = *(const short8*)(Bsm + (gf * 16 + l16) * 64 + sl);
                acc[c] = __builtin_amdgcn_mfma_f32_16x16x32_bf16(af, bf, acc[c], 0, 0, 0);
            }
        }
        __syncthreads();
    }

    if constexpr (EPI != EPR_HZ) {
        #pragma unroll
        for (int c = 0; c < NF; ++c) {
            const int gf = (EPI == EPR_BCDT) ? (wave + 4 * c) : (wave * NF + c);
            const float bs = bias[gf * 16 + l16];
            #pragma unroll
            for (int r = 0; r < 4; ++r) acc[c][r] += bs;
        }
    }

    if constexpr (EPI == EPR_LNSILU) {
        float s[4], q[4];
        #pragma unroll
        for (int r = 0; r < 4; ++r) {
            s[r] = 0.f; q[r] = 0.f;
            #pragma unroll
            for (int c = 0; c < NF; ++c) { const float v = acc[c][r]; s[r] += v; q[r] += v * v; }
            #pragma unroll
            for (int o = 1; o < 16; o <<= 1) { s[r] += __shfl_xor(s[r], o); q[r] += __shfl_xor(q[r], o); }
        }
        if (l16 == 0) {
            #pragma unroll
            for (int r = 0; r < 4; ++r) {
                red[(quad * 4 + r) * 8 + wave * 2]     = s[r];
                red[(quad * 4 + r) * 8 + wave * 2 + 1] = q[r];
            }
        }
        __syncthreads();
        #pragma unroll
        for (int r = 0; r < 4; ++r) {
            const int row16 = quad * 4 + r;
            float S = 0.f, Q = 0.f;
            #pragma unroll
            for (int w = 0; w < 4; ++w) { S += red[row16 * 8 + w * 2]; Q += red[row16 * 8 + w * 2 + 1]; }
            const float mean = S * (1.f / N);
            const float rstd = rsqrtf(Q * (1.f / N) - mean * mean + 1e-5f);
            #pragma unroll
            for (int c = 0; c < NF; ++c) {
                const int col = (wave * NF + c) * 16 + l16;
                const float y = (acc[c][r] - mean) * rstd * q0[col] + q1[col];
                outb[(size_t)(m0 + row16) * N + col] = f2b(y / (1.f + __expf(-y)));
            }
        }
    } else if constexpr (EPI == EPR_BCDT) {
        float t[2][4], e[2][4];
        #pragma unroll
        for (int ci = 0; ci < 2; ++ci) {
            const int dcol = (wave + 4 * (ci + 4)) * 16 - 256 + l16;
            const float av = q0[dcol];
            #pragma unroll
            for (int r = 0; r < 4; ++r) t[ci][r] = acc[ci + 4][r] + av;
        }
        float pm[4];
        #pragma unroll
        for (int r = 0; r < 4; ++r) {
            pm[r] = fmaxf(t[0][r], t[1][r]);
            #pragma unroll
            for (int o = 1; o < 16; o <<= 1) pm[r] = fmaxf(pm[r], __shfl_xor(pm[r], o));
        }
        if (l16 == 0) {
            #pragma unroll
            for (int r = 0; r < 4; ++r) red[(quad * 4 + r) * 4 + wave] = pm[r];
        }
        __syncthreads();
        float mx[4];
        #pragma unroll
        for (int r = 0; r < 4; ++r) {
            const int row16 = quad * 4 + r;
            mx[r] = fmaxf(fmaxf(red[row16 * 4], red[row16 * 4 + 1]),
                          fmaxf(red[row16 * 4 + 2], red[row16 * 4 + 3]));
        }
        float pe[4], pc2[4];
        #pragma unroll
        for (int r = 0; r < 4; ++r) {
            e[0][r] = __expf(t[0][r] - mx[r]);
            e[1][r] = __expf(t[1][r] - mx[r]);
            pe[r] = e[0][r] + e[1][r];
            pc2[r] = 0.f;
            #pragma unroll
            for (int ci = 0; ci < 2; ++ci) {
                const int ccol = (wave + 4 * (ci + 2)) * 16 - 128 + l16;
                pc2[r] += acc[ci + 2][r] * q1[ccol];
            }
            #pragma unroll
            for (int o = 1; o < 16; o <<= 1) { pe[r] += __shfl_xor(pe[r], o); pc2[r] += __shfl_xor(pc2[r], o); }
        }
        if (l16 == 0) {
            #pragma unroll
            for (int r = 0; r < 4; ++r) {
                red[64  + (quad * 4 + r) * 4 + wave] = pe[r];
                red[128 + (quad * 4 + r) * 4 + wave] = pc2[r];
            }
        }
        __syncthreads();
        #pragma unroll
        for (int r = 0; r < 4; ++r) {
            const int row16 = quad * 4 + r;
            const float inv = 1.f / (red[64 + row16 * 4] + red[64 + row16 * 4 + 1] +
                                     red[64 + row16 * 4 + 2] + red[64 + row16 * 4 + 3]);
            #pragma unroll
            for (int ci = 0; ci < 2; ++ci) {
                const int bcol = (wave + 4 * ci) * 16 + l16;
                outb[(size_t)(m0 + row16) * 128 + bcol] = f2b(acc[ci][r] * e[ci][r] * inv);
            }
        }
        if (wave == 0 && l16 == 0) {
            #pragma unroll
            for (int r = 0; r < 4; ++r) {
                const int row16 = quad * 4 + r;
                outf[m0 + row16] = 1.f + red[128 + row16 * 4] + red[128 + row16 * 4 + 1] +
                                   red[128 + row16 * 4 + 2] + red[128 + row16 * 4 + 3] + q2[0];
            }
        }
    } else if constexpr (EPI == EPR_HZ) {
        float* ep = (float*)Bsm;
        const float D0 = q0[0];
        if (wave >= 2) {
            #pragma unroll
            for (int c = 0; c < NF; ++c) {
                const int lc = (wave * NF + c) * 16 + l16;
                const float bz = bias[512 + by * 256 + lc - 256];
                #pragma unroll
                for (int r = 0; r < 4; ++r) {
                    const float z = acc[c][r] + bz;
                    ep[(quad * 4 + r) * 256 + lc - 256] = z / (1.f + __expf(-z)) + D0;
                }
            }
        }
        __syncthreads();
        if (wave < 2) {
            #pragma unroll
            for (int c = 0; c < NF; ++c) {
                const int lc = (wave * NF + c) * 16 + l16;
                const float bh = bias[by * 256 + lc];
                #pragma unroll
                for (int r = 0; r < 4; ++r) {
                    const float v = (acc[c][r] + bh) * ep[(quad * 4 + r) * 256 + lc];
                    outb[(size_t)(m0 + quad * 4 + r) * 512 + by * 256 + lc] = f2b(v);
                }
            }
        }
    } else {  // EPR_FINAL
        float fv[NF][4], s[4], q[4];
        #pragma unroll
        for (int r = 0; r < 4; ++r) { s[r] = 0.f; q[r] = 0.f; }
        #pragma unroll
        for (int c = 0; c < NF; ++c) {
            const int col = (wave * NF + c) * 16 + l16;
            #pragma unroll
            for (int r = 0; r < 4; ++r) {
                const size_t idx = (size_t)(m0 + quad * 4 + r) * 256 + col;
                const float g = 1.f / (1.f + __expf(-acc[c][r]));
                const float f = g * q0[idx] + (1.f - g) * q1[idx] + q2[idx];
                fv[c][r] = f; s[r] += f; q[r] += f * f;
            }
        }
        #pragma unroll
        for (int r = 0; r < 4; ++r) {
            #pragma unroll
            for (int o = 1; o < 16; o <<= 1) { s[r] += __shfl_xor(s[r], o); q[r] += __shfl_xor(q[r], o); }
        }
        if (l16 == 0) {
            #pragma unroll
            for (int r = 0; r < 4; ++r) {
                red[(quad * 4 + r) * 8 + wave * 2]     = s[r];
                red[(quad * 4 + r) * 8 + wave * 2 + 1] = q[r];
            }
        }
        __syncthreads();
        #pragma unroll
        for (int r = 0; r < 4; ++r) {
            const int row16 = quad * 4 + r;
            float S = 0.f, Q = 0.f;
            #pragma unroll
            for (int w = 0; w < 4; ++w) { S += red[row16 * 8 + w * 2]; Q += red[row16 * 8 + w * 2 + 1]; }
            const float mean = S * (1.f / 256.f);
            const float rstd = rsqrtf(Q * (1.f / 256.f) - mean * mean + 1e-5f);
            #pragma unroll
            for (int c = 0; c < NF; ++c) {
                const int col = (wave * NF + c) * 16 + l16;
                outf[(size_t)(m0 + row16) * 256 + col] = (fv[c][r] - mean) * rstd * q3[col] + q4[col];
            }
        }
    }
}

// ---------------------------------------------------------------------------
// Fused GAT attention v8: BARRIER-FREE, ZERO-LDS, fragment-major WhF.
// Wave-independent streaming: per 32-j chunk, each wave
//   1) coalesced adj/dA loads (thread t: row t>>2, j-group t&3, 32B/row-seg)
//   2) leaky+exp+pack -> 8 ds_bpermute (fixed in-wave permutation) -> A-frags
//   3) 8 coalesced 16B B-frag loads from WhF + 16 MFMA.
// No __syncthreads, no global_load_lds -> compiler pipelines freely; waves
// hide adj HBM latency. Grid (128, 4 js): 512 blocks.
// ---------------------------------------------------------------------------
__global__ __launch_bounds__(256) void attn_kernel(
    const int* __restrict__ adj, const float* __restrict__ sA,
    const float* __restrict__ dA, const ushort* __restrict__ WhF,
    float* __restrict__ Upart, float* __restrict__ lpart)
{
    const int tid  = threadIdx.x;
    const int wave = tid >> 6, lane = tid & 63, quad = lane >> 4, l16 = lane & 15;
    const int i0 = blockIdx.x * 64;
    const int js = blockIdx.y;
    const int jbase = js * 2048;
    const int jb0 = jbase >> 5;
    const int rt = wave & 1, ch = wave >> 1;
    const int rr = lane >> 2, jg = lane & 3;        // P-compute row / j-group
    const int row0 = i0 + rt * 32 + rr;
    const int row1 = row0 + 16;
    const float s0 = sA[row0], s1 = sA[row1];
    const int* adj0 = adj + (size_t)row0 * 8192 + jbase + jg * 8;
    const int* adj1 = adj + (size_t)row1 * 8192 + jbase + jg * 8;
    const float* dAp = dA + jbase + jg * 8;
    const int perm = ((l16 << 2) | quad) << 2;      // bpermute byte addr

    f32x4 zero = {0.f, 0.f, 0.f, 0.f};
    f32x4 acc[2][8] = {{zero, zero, zero, zero, zero, zero, zero, zero},
                       {zero, zero, zero, zero, zero, zero, zero, zero}};
    float ls0 = 0.f, ls1 = 0.f;

    #pragma unroll 2
    for (int cb = 0; cb < 64; ++cb) {
        const int off = cb * 32;
        const float4 d0 = *(const float4*)(dAp + off);
        const float4 d1 = *(const float4*)(dAp + off + 4);
        const int4 a00 = *(const int4*)(adj0 + off);
        const int4 a01 = *(const int4*)(adj0 + off + 4);
        const int4 a10 = *(const int4*)(adj1 + off);
        const int4 a11 = *(const int4*)(adj1 + off + 4);
        const float dd[8] = {d0.x, d0.y, d0.z, d0.w, d1.x, d1.y, d1.z, d1.w};
        const int aa0[8] = {a00.x, a00.y, a00.z, a00.w, a01.x, a01.y, a01.z, a01.w};
        const int aa1[8] = {a10.x, a10.y, a10.z, a10.w, a11.x, a11.y, a11.z, a11.w};
        ushort us0[8], us1[8];
        #pragma unroll
        for (int q = 0; q < 8; ++q) {
            float e0 = s0 + dd[q];
            e0 = fmaxf(e0, 0.2f * e0);
            const float w0 = aa0[q] ? __expf(e0) : 0.f;
            ls0 += w0; us0[q] = f2b(w0);
            float e1 = s1 + dd[q];
            e1 = fmaxf(e1, 0.2f * e1);
            const float w1 = aa1[q] ? __expf(e1) : 0.f;
            ls1 += w1; us1[q] = f2b(w1);
        }
        union FR { int d[4]; short8 v; } f0, f1;
        #pragma unroll
        for (int d = 0; d < 4; ++d) {
            const int p0 = (int)((uint)us0[2 * d] | ((uint)us0[2 * d + 1] << 16));
            const int p1 = (int)((uint)us1[2 * d] | ((uint)us1[2 * d + 1] << 16));
            f0.d[d] = __builtin_amdgcn_ds_bpermute(perm, p0);
            f1.d[d] = __builtin_amdgcn_ds_bpermute(perm, p1);
        }
        const ushort* Bp = WhF + ((size_t)((jb0 + cb) * 16 + ch * 8) * 64 + lane) * 8;
        #pragma unroll
        for (int c = 0; c < 8; ++c) {
            short8 bf = *(const short8*)(Bp + (size_t)c * 64 * 8);
            acc[0][c] = __builtin_amdgcn_mfma_f32_16x16x32_bf16(f0.v, bf, acc[0][c], 0, 0, 0);
            acc[1][c] = __builtin_amdgcn_mfma_f32_16x16x32_bf16(f1.v, bf, acc[1][c], 0, 0, 0);
        }
    }

    // row sums: fold the 4 j-group threads (consecutive lanes) per row
    ls0 += __shfl_down(ls0, 1); ls0 += __shfl_down(ls0, 2);
    ls1 += __shfl_down(ls1, 1); ls1 += __shfl_down(ls1, 2);
    if (ch == 0 && jg == 0) {
        lpart[(size_t)js * 8192 + row0] = ls0;
        lpart[(size_t)js * 8192 + row1] = ls1;
    }

    #pragma unroll
    for (int it = 0; it < 2; ++it) {
        #pragma unroll
        for (int c = 0; c < 8; ++c) {
            const int col = ch * 128 + c * 16 + l16;
            #pragma unroll
            for (int r = 0; r < 4; ++r) {
                const int row = i0 + rt * 32 + it * 16 + quad * 4 + r;
                Upart[((size_t)js * 8192 + row) * 256 + col] = acc[it][c][r];
            }
        }
    }
}

// ---------------------------------------------------------------------------
// post_attn: blocks [0,2048) combine; [2048,2560) fe1+LN+silu; [2560,3072) bcdt
// ---------------------------------------------------------------------------
__global__ __launch_bounds__(256) void post_attn_kernel(
    const float* __restrict__ Upart, const float* __restrict__ lpart,
    float* __restrict__ hattn, ushort* __restrict__ comb,
    const ushort* __restrict__ Whbf,
    const ushort* __restrict__ fe1T, const float* __restrict__ fe1_b,
    const float* __restrict__ fe_ln_g, const float* __restrict__ fe_ln_b,
    ushort* __restrict__ tact,
    const ushort* __restrict__ bcdtT, const float* __restrict__ b_bcdt,
    const float* __restrict__ Avec, const float* __restrict__ cpw,
    const float* __restrict__ cpb,
    ushort* __restrict__ SB, float* __restrict__ cscl)
{
    __shared__ ushort Asm[16 * 64];
    __shared__ ushort Bsm[512 * 64];
    __shared__ float red[192];
    const int b = blockIdx.x;

    if (b < 2048) {
        const int row = b * 4 + (threadIdx.x >> 6);
        const int lane = threadIdx.x & 63;
        float l = 0.f;
        #pragma unroll
        for (int js = 0; js < 4; ++js) l += lpart[(size_t)js * 8192 + row];
        const float inv = 1.f / l;
        float4 u = {0.f, 0.f, 0.f, 0.f};
        #pragma unroll
        for (int js = 0; js < 4; ++js) {
            const float4 t = *(const float4*)&Upart[((size_t)js * 8192 + row) * 256 + lane * 4];
            u.x += t.x; u.y += t.y; u.z += t.z; u.w += t.w;
        }
        u.x *= inv; u.y *= inv; u.z *= inv; u.w *= inv;
        *(float4*)&hattn[(size_t)row * 256 + lane * 4] = u;
        union { ushort us[4]; uint2 v; } pk;
        pk.us[0] = f2b(u.x); pk.us[1] = f2b(u.y); pk.us[2] = f2b(u.z); pk.us[3] = f2b(u.w);
        *(uint2*)&comb[(size_t)row * 512 + lane * 4] = pk.v;
    } else if (b < 2560) {
        gemm_row_dev<256, 512, EPR_LNSILU>(Whbf, fe1T, fe1_b, nullptr, tact,
            fe_ln_g, fe_ln_b, nullptr, nullptr, nullptr, b - 2048, 0, Asm, Bsm, red);
    } else {
        gemm_row_dev<256, 384, EPR_BCDT>(Whbf, bcdtT, b_bcdt, cscl, SB,
            Avec, cpw, cpb, nullptr, nullptr, b - 2560, 0, Asm, Bsm, red);
    }
}

__global__ __launch_bounds__(256) void gemm_fe2_sb_kernel(
    const ushort* __restrict__ tact, const ushort* __restrict__ fe2T,
    const float* __restrict__ fe2_b, float* __restrict__ henh,
    const ushort* __restrict__ SB, const ushort* __restrict__ abpT,
    const float* __restrict__ abp_b, ushort* __restrict__ hsbf,
    const float* __restrict__ Wh)
{
    __shared__ ushort Asm[64 * 64];
    __shared__ ushort Bsm[64 * 64];
    const int b = blockIdx.x;
    if (b < 512)
        gemm_k_dev<512, EPI_F32>(tact, fe2T, fe2_b, 256, henh, nullptr, 0, 0,
                                 nullptr, b & 127, b >> 7, Asm, Bsm);
    else
        gemm_k_dev<128, EPI_MUL_BF16>(SB, abpT, abp_b, 256, nullptr, hsbf, 256, 0,
                                      Wh, (b - 512) & 127, (b - 512) >> 7, Asm, Bsm);
}

__global__ __launch_bounds__(256) void gemm_hz_kernel(
    const ushort* __restrict__ hsbf, const ushort* __restrict__ hzT,
    const float* __restrict__ b_hz, ushort* __restrict__ vbf,
    const float* __restrict__ Dvec)
{
    __shared__ ushort Asm[16 * 64];
    __shared__ ushort Bsm[512 * 64];
    __shared__ float red[192];
    gemm_row_dev<256, 512, EPR_HZ>(hsbf, hzT, b_hz, nullptr, vbf, Dvec,
        nullptr, nullptr, nullptr, nullptr, blockIdx.x, blockIdx.y, Asm, Bsm, red);
}

__global__ __launch_bounds__(256) void gemm_out_kernel(
    const ushort* __restrict__ vbf, const ushort* __restrict__ outT,
    const float* __restrict__ out_b, float* __restrict__ hs2,
    ushort* __restrict__ comb, const float* __restrict__ cscl)
{
    __shared__ ushort Asm[64 * 64];
    __shared__ ushort Bsm[64 * 64];
    gemm_k_dev<512, EPI_SCALE_FB>(vbf, outT, out_b, 256, hs2, comb, 512, 256,
                                  cscl, blockIdx.x, blockIdx.y, Asm, Bsm);
}

__global__ __launch_bounds__(256) void gemm_g1_kernel(
    const ushort* __restrict__ comb, const ushort* __restrict__ g1T,
    const float* __restrict__ g1_b, ushort* __restrict__ tact,
    const float* __restrict__ g_ln_g, const float* __restrict__ g_ln_b)
{
    __shared__ ushort Asm[16 * 64];
    __shared__ ushort Bsm[512 * 64];
    __shared__ float red[192];
    gemm_row_dev<512, 512, EPR_LNSILU>(comb, g1T, g1_b, nullptr, tact,
        g_ln_g, g_ln_b, nullptr, nullptr, nullptr, blockIdx.x, 0, Asm, Bsm, red);
}

__global__ __launch_bounds__(256) void gemm_final_kernel(
    const ushort* __restrict__ tact, const ushort* __restrict__ g2T,
    const float* __restrict__ g2_b, float* __restrict__ outp,
    const float* __restrict__ hattn, const float* __restrict__ hs2,
    const float* __restrict__ henh, const float* __restrict__ ln_g,
    const float* __restrict__ ln_b)
{
    __shared__ ushort Asm[16 * 64];
    __shared__ ushort Bsm[256 * 64];
    __shared__ float red[192];
    gemm_row_dev<512, 256, EPR_FINAL>(tact, g2T, g2_b, outp, nullptr,
        hattn, hs2, henh, ln_g, ln_b, blockIdx.x, 0, Asm, Bsm, red);
}

// ---------------------------------------------------------------------------
// Descriptor-driven transpose/cast mega-kernel (+ hz column permutation)
// ---------------------------------------------------------------------------
struct TJob { const float* in; ushort* out; int R, C, off, perm; };
struct TArgs { TJob j[10]; };

DEVINL int hzperm(int j) {
    return (j < 512) ? ((j >> 8) << 9) + (j & 255)
                     : (((j - 512) >> 8) << 9) + 256 + ((j - 512) & 255);
}

__global__ __launch_bounds__(256) void multi_transpose_kernel(TArgs a)
{
    __shared__ float tile[32][33];
    const int b = blockIdx.x;
    int ji = 0;
    #pragma unroll
    for (int k = 1; k < 10; ++k) if (b >= a.j[k].off) ji = k;
    const TJob J = a.j[ji];
    const int t = b - J.off;

    if (J.R == 0) {
        const int base = t * 1024 + threadIdx.x;
        #pragma unroll
        for (int k = 0; k < 4; ++k)
            J.out[base + k * 256] = f2b(J.in[base + k * 256]);
        return;
    }
    const int CB = J.C >> 5;
    const int bx = t % CB, by = t / CB;
    const int tx = threadIdx.x & 31, ty = threadIdx.x >> 5;
    const int c0 = bx * 32, r0 = by * 32;
    #pragma unroll
    for (int i = ty; i < 32; i += 8)
        tile[i][tx] = J.in[(size_t)(r0 + i) * J.C + (c0 + tx)];
    __syncthreads();
    #pragma unroll
    for (int i = ty; i < 32; i += 8) {
        int orow = c0 + i;
        if (J.perm) orow = hzperm(orow);
        J.out[(size_t)orow * J.R + (r0 + tx)] = f2b(tile[tx][i]);
    }
}

// ---------------------------------------------------------------------------
extern "C" void kernel_launch(void* const* d_in, const int* in_sizes, int n_in,
                              void* d_out, int out_size, void* d_ws, size_t ws_size,
                              hipStream_t stream)
{
    const float* h      = (const float*)d_in[0];
    const int*   adj    = (const int*)  d_in[1];
    const float* W      = (const float*)d_in[2];
    const float* a_src  = (const float*)d_in[3];
    const float* a_dst  = (const float*)d_in[4];
    const float* W_bcdt = (const float*)d_in[5];
    const float* b_bcdt = (const float*)d_in[6];
    const float* abp_w  = (const float*)d_in[7];
    const float* abp_b  = (const float*)d_in[8];
    const float* cp_w   = (const float*)d_in[9];
    const float* cp_b   = (const float*)d_in[10];
    const float* W_hz   = (const float*)d_in[11];
    const float* b_hz   = (const float*)d_in[12];
    const float* out_w  = (const float*)d_in[13];
    const float* out_b  = (const float*)d_in[14];
    const float* fe1_w  = (const float*)d_in[15];
    const float* fe1_b  = (const float*)d_in[16];
    const float* fe_ln_g= (const float*)d_in[17];
    const float* fe_ln_b= (const float*)d_in[18];
    const float* fe2_w  = (const float*)d_in[19];
    const float* fe2_b  = (const float*)d_in[20];
    const float* Avec   = (const float*)d_in[21];
    const float* Dvec   = (const float*)d_in[22];
    const float* g1_w   = (const float*)d_in[23];
    const float* g1_b   = (const float*)d_in[24];
    const float* g_ln_g = (const float*)d_in[25];
    const float* g_ln_b = (const float*)d_in[26];
    const float* g2_w   = (const float*)d_in[27];
    const float* g2_b   = (const float*)d_in[28];
    const float* ln_g   = (const float*)d_in[29];
    const float* ln_b   = (const float*)d_in[30];
    float* outp = (float*)d_out;

    char* p = (char*)d_ws;
    size_t off = 0;
    auto take = [&](size_t nbytes) -> void* {
        void* r = p + off;
        off += (nbytes + 255) & ~(size_t)255;
        return r;
    };
    ushort* wT    = (ushort*)take(256 * 256 * 2);
    ushort* fe1T  = (ushort*)take(512 * 256 * 2);
    ushort* fe2T  = (ushort*)take(256 * 512 * 2);
    ushort* bcdtT = (ushort*)take(384 * 256 * 2);
    ushort* hzT   = (ushort*)take(1024 * 256 * 2);
    ushort* outT  = (ushort*)take(256 * 512 * 2);
    ushort* g1T   = (ushort*)take(512 * 512 * 2);
    ushort* g2T   = (ushort*)take(256 * 512 * 2);
    ushort* abpT  = (ushort*)take(256 * 128 * 2);
    ushort* hbf   = (ushort*)take((size_t)8192 * 256 * 2);
    float*  Wh    = (float*) take((size_t)8192 * 256 * 4);
    ushort* Whbf  = (ushort*)take((size_t)8192 * 256 * 2);
    ushort* WhF   = (ushort*)take((size_t)8192 * 256 * 2);   // fragment-major
    float*  sbuf  = (float*) take(8192 * 4);
    float*  dbuf  = (float*) take(8192 * 4);
    float*  cscl  = (float*) take(8192 * 4);
    float*  hattn = (float*) take((size_t)8192 * 256 * 4);
    float*  henh  = (float*) take((size_t)8192 * 256 * 4);
    float*  lpart = (float*) take(4 * 8192 * 4);
    ushort* SB    = (ushort*)take((size_t)8192 * 128 * 2);
    ushort* hsbf  = (ushort*)take((size_t)8192 * 256 * 2);
    ushort* vbf   = (ushort*)take((size_t)8192 * 512 * 2);
    float*  hs2   = (float*) take((size_t)8192 * 256 * 4);
    ushort* comb  = (ushort*)take((size_t)8192 * 512 * 2);
    ushort* tact  = (ushort*)take((size_t)8192 * 512 * 2);
    float*  Upart = (float*) take((size_t)4 * 8192 * 256 * 4);

    (void)in_sizes; (void)n_in; (void)out_size; (void)ws_size;

    hipMemsetAsync(sbuf, 0, 2 * 8192 * sizeof(float), stream);

    // 1) all weight transposes + h cast
    {
        TArgs ta; int boff = 0;
        auto addT = [&](int i, const float* in, ushort* out, int R, int C, int perm) {
            ta.j[i] = TJob{in, out, R, C, boff, perm};
            boff += (R / 32) * (C / 32);
        };
        addT(0, W,      wT,    256, 256,  0);
        addT(1, fe1_w,  fe1T,  256, 512,  0);
        addT(2, fe2_w,  fe2T,  512, 256,  0);
        addT(3, W_bcdt, bcdtT, 256, 384,  0);
        addT(4, abp_w,  abpT,  128, 256,  0);
        addT(5, W_hz,   hzT,   256, 1024, 1);
        addT(6, out_w,  outT,  512, 256,  0);
        addT(7, g1_w,   g1T,   512, 512,  0);
        addT(8, g2_w,   g2T,   512, 256,  0);
        ta.j[9] = TJob{h, hbf, 0, 8192 * 256, boff, 0};
        boff += (8192 * 256) / 1024;
        multi_transpose_kernel<<<boff, 256, 0, stream>>>(ta);
    }

    // 2) Wh gemm (Wh f32 + Whbf + WhF + s/d dots)
    gemm_wh_kernel<<<dim3(128, 4), 256, 0, stream>>>(
        hbf, wT, a_src, a_dst, Wh, Whbf, WhF, sbuf, dbuf);

    // 3) attention (barrier-free, fragment-major, js=4)
    attn_kernel<<<dim3(128, 4), 256, 0, stream>>>(adj, sbuf, dbuf, WhF, Upart, lpart);

    // 4) combine + fe1(+LN+silu) + bcdt(+softmax+cscale)
    post_attn_kernel<<<3072, 256, 0, stream>>>(
        Upart, lpart, hattn, comb, Whbf,
        fe1T, fe1_b, fe_ln_g, fe_ln_b, tact,
        bcdtT, b_bcdt, Avec, cp_w, cp_b, SB, cscl);

    // 5) fe2 + SB gemm
    gemm_fe2_sb_kernel<<<1024, 256, 0, stream>>>(
        tact, fe2T, fe2_b, henh, SB, abpT, abp_b, hsbf, Wh);

    // 6) hz (+ h*(silu(z)+D))
    gemm_hz_kernel<<<dim3(512, 2), 256, 0, stream>>>(hsbf, hzT, b_hz, vbf, Dvec);

    // 7) out gemm (*cscale)
    gemm_out_kernel<<<dim3(128, 4), 256, 0, stream>>>(vbf, outT, out_b, hs2, comb, cscl);

    // 8) g1 (+LN+silu)
    gemm_g1_kernel<<<512, 256, 0, stream>>>(comb, g1T, g1_b, tact, g_ln_g, g_ln_b);

    // 9) g2 + sigmoid + gated fuse + final LN
    gemm_final_kernel<<<512, 256, 0, stream>>>(
        tact, g2T, g2_b, outp, hattn, hs2, henh, ln_g, ln_b);
}